// Round 1
// baseline (253.654 us; speedup 1.0000x reference)
//
#include <hip/hip_runtime.h>
#include <math.h>

#define NROWS 8192
#define KDIM  768
#define BM 128
#define BN 128
#define BK 64
#define KTILES (KDIM / BK)   // 12

typedef short bf16x8 __attribute__((ext_vector_type(8)));  // 8 bf16 = 4 VGPRs (per guide §3)
typedef float f32x4  __attribute__((ext_vector_type(4)));

static __device__ __forceinline__ unsigned short f2bf_rne(float f) {
    unsigned x = __float_as_uint(f);
    unsigned r = x + 0x7fffu + ((x >> 16) & 1u);   // round-to-nearest-even
    return (unsigned short)(r >> 16);
}
// monotonic float<->uint encoding so atomicMax(uint) == float max
static __device__ __forceinline__ unsigned enc_f(float f) {
    unsigned x = __float_as_uint(f);
    return (x & 0x80000000u) ? ~x : (x | 0x80000000u);
}
static __device__ __forceinline__ float dec_f(unsigned u) {
    unsigned x = (u & 0x80000000u) ? (u ^ 0x80000000u) : ~u;
    return __uint_as_float(x);
}

__global__ void init_out_k(unsigned* __restrict__ out) {
    out[blockIdx.x * 256 + threadIdx.x] = enc_f(-INFINITY);  // 0x007FFFFF
}

__global__ __launch_bounds__(256) void normalize_cvt_k(
        const float* __restrict__ ex, const float* __restrict__ ey,
        unsigned short* __restrict__ dst_base) {
    const int row = blockIdx.x;
    const float* src = blockIdx.y ? ey : ex;
    unsigned short* dst = dst_base + (size_t)blockIdx.y * NROWS * KDIM;
    const float* xr = src + (size_t)row * KDIM;
    const int t = threadIdx.x;                 // 768 = 256*3
    float v0 = xr[t], v1 = xr[t + 256], v2 = xr[t + 512];
    float ss = v0 * v0 + v1 * v1 + v2 * v2;
    #pragma unroll
    for (int off = 32; off > 0; off >>= 1) ss += __shfl_xor(ss, off);
    __shared__ float red[4];
    if ((t & 63) == 0) red[t >> 6] = ss;
    __syncthreads();
    float scale = 1.0f / fmaxf(sqrtf(red[0] + red[1] + red[2] + red[3]), 1e-8f);
    unsigned short* dr = dst + (size_t)row * KDIM;
    dr[t]       = f2bf_rne(v0 * scale);
    dr[t + 256] = f2bf_rne(v1 * scale);
    dr[t + 512] = f2bf_rne(v2 * scale);
}

// A = exn bf16 [8192][768] (rows = output rows m)
// B = eyn bf16 [8192][768] (rows = output cols n; sims = A . B^T)
__global__ __launch_bounds__(256) void gemm_rowmax_k(
        const unsigned short* __restrict__ A,
        const unsigned short* __restrict__ B,
        unsigned* __restrict__ out) {
    // LDS tiles, row-major [row][k], 8 chunks of 16B per row, chunk slot = gchunk ^ (row&7)
    __shared__ unsigned short As[BM * BK];   // 16 KB
    __shared__ unsigned short Bs[BN * BK];   // 16 KB

    const int tid  = threadIdx.x;
    const int wave = tid >> 6, lane = tid & 63;
    const int br = blockIdx.y, bc = blockIdx.x;

    // ---- staging geometry: each issue = 1 wave covers 8 rows x 128B, lane L -> ldsbase + L*16
    const int srow   = lane >> 3;              // 0..7 row within chunk-of-8
    const int gchunk = (lane & 7) ^ srow;      // xor-swizzle: slot (lane&7) holds global chunk gchunk
    const int scol   = gchunk * 8;             // shorts

    const unsigned short* gA[4]; const unsigned short* gB[4];
    unsigned short* lA[4]; unsigned short* lB[4];
    #pragma unroll
    for (int i = 0; i < 4; ++i) {
        int chunk = wave + 4 * i;              // 0..15, 8 rows each
        gA[i] = A + (size_t)(br * BM + chunk * 8 + srow) * KDIM + scol;
        gB[i] = B + (size_t)(bc * BN + chunk * 8 + srow) * KDIM + scol;
        lA[i] = As + chunk * 512;              // 8 rows * 64 shorts
        lB[i] = Bs + chunk * 512;
    }

    // ---- compute geometry: 4 waves as 2x2, each wave 64x64, 4x4 tiles of 16x16x32
    const int wm = (wave >> 1) * 64, wn = (wave & 1) * 64;
    const int quad = lane >> 4, mrow = lane & 15;
    const int c0 = quad ^ (mrow & 7);          // swizzled chunk slot for ks=0 (ks=1: c0^4)
    const unsigned short* aBase = As + (wm + mrow) * BK;
    const unsigned short* bBase = Bs + (wn + mrow) * BK;

    f32x4 acc[4][4] = {};

    for (int kt = 0; kt < KTILES; ++kt) {
        __syncthreads();   // previous tile's reads done before overwrite
        #pragma unroll
        for (int i = 0; i < 4; ++i) {
            __builtin_amdgcn_global_load_lds(
                (const __attribute__((address_space(1))) void*)gA[i],
                (__attribute__((address_space(3))) void*)lA[i], 16, 0, 0);
            __builtin_amdgcn_global_load_lds(
                (const __attribute__((address_space(1))) void*)gB[i],
                (__attribute__((address_space(3))) void*)lB[i], 16, 0, 0);
            gA[i] += BK; gB[i] += BK;
        }
        __syncthreads();   // drains vmcnt: staging complete

        #pragma unroll
        for (int ks = 0; ks < 2; ++ks) {
            const int ck = c0 ^ (ks ? 4 : 0);
            bf16x8 af[4], bfr[4];
            #pragma unroll
            for (int mi = 0; mi < 4; ++mi)
                af[mi] = *(const bf16x8*)(aBase + mi * 16 * BK + ck * 8);
            #pragma unroll
            for (int ni = 0; ni < 4; ++ni)
                bfr[ni] = *(const bf16x8*)(bBase + ni * 16 * BK + ck * 8);
            #pragma unroll
            for (int mi = 0; mi < 4; ++mi)
                #pragma unroll
                for (int ni = 0; ni < 4; ++ni)
                    acc[mi][ni] = __builtin_amdgcn_mfma_f32_16x16x32_bf16(
                        af[mi], bfr[ni], acc[mi][ni], 0, 0, 0);
        }
    }

    // ---- epilogue: row-max over this wave's 64 columns, then atomic merge
    // C/D layout: col = lane&15, row = quad*4 + reg  (guide §3, m89-verified)
    const int row0 = br * BM + wm + quad * 4;
    #pragma unroll
    for (int mi = 0; mi < 4; ++mi) {
        #pragma unroll
        for (int r = 0; r < 4; ++r) {
            float v = fmaxf(fmaxf(acc[mi][0][r], acc[mi][1][r]),
                            fmaxf(acc[mi][2][r], acc[mi][3][r]));
            v = fmaxf(v, __shfl_xor(v, 1));
            v = fmaxf(v, __shfl_xor(v, 2));
            v = fmaxf(v, __shfl_xor(v, 4));
            v = fmaxf(v, __shfl_xor(v, 8));
            if (mrow == 0)
                atomicMax(&out[row0 + mi * 16 + r], enc_f(v));
        }
    }
}

__global__ void decode_out_k(unsigned* __restrict__ u) {
    int i = blockIdx.x * 256 + threadIdx.x;
    float v = dec_f(u[i]);
    ((float*)u)[i] = v;
}

extern "C" void kernel_launch(void* const* d_in, const int* in_sizes, int n_in,
                              void* d_out, int out_size, void* d_ws, size_t ws_size,
                              hipStream_t stream) {
    (void)in_sizes; (void)n_in; (void)out_size; (void)ws_size;
    const float* ex = (const float*)d_in[0];
    const float* ey = (const float*)d_in[1];
    unsigned short* wsb = (unsigned short*)d_ws;     // exn[8192*768] ++ eyn[8192*768] bf16 (25.2 MB)
    unsigned* outu = (unsigned*)d_out;

    init_out_k<<<NROWS / 256, 256, 0, stream>>>(outu);
    normalize_cvt_k<<<dim3(NROWS, 2), 256, 0, stream>>>(ex, ey, wsb);
    gemm_rowmax_k<<<dim3(NROWS / BN, NROWS / BM), 256, 0, stream>>>(
        wsb, wsb + (size_t)NROWS * KDIM, outu);
    decode_out_k<<<NROWS / 256, 256, 0, stream>>>(outu);
}